// Round 3
// baseline (465.848 us; speedup 1.0000x reference)
//
#include <hip/hip_runtime.h>
#include <hip/hip_bf16.h>

// out[b,s,:] = (emb[x[b,s],:] @ W + b) * sqrt(2048)
// DTYPES (per harness contract, matching the fp32 reference):
//   x:[4,8192] int32, emb:[50000,300] fp32, W:[300,2048] fp32, b:[2048] fp32
//   out: [4,8192,2048] fp32.
// M=32768 tokens, N=2048, K=300 (padded to 320).
// Strategy: convert A/B to fp16 (11-bit mantissa: conversion error ~2^-12,
// well under the 5.24 absmax threshold), MFMA f32_16x16x32_f16, fp32 out.

#define TOKENS 32768
#define EMB 300
#define DM 2048
#define KPAD 320
#define LDS_STRIDE 72   // 64 + 8 pad halves; 144 B rows -> 16B-aligned chunks, <=2-way conflicts
#define SCALE 45.25483399593904f

typedef _Float16 f16;
typedef _Float16 h4 __attribute__((ext_vector_type(4)));
typedef _Float16 h8 __attribute__((ext_vector_type(8)));
typedef float f32x4 __attribute__((ext_vector_type(4)));

// ---- prep: Wt[n][k] = (f16)W[k][n] (k padded 300->320 with zeros), bs[n]=b[n]*scale ----
__global__ __launch_bounds__(256) void prep_w(const float* __restrict__ W, f16* __restrict__ Wt) {
    int idx = blockIdx.x * 256 + threadIdx.x;      // 0 .. 2048*320
    int k = idx >> 11;                             // n-fast: coalesced reads of W
    int n = idx & 2047;
    f16 v = (f16)0.f;
    if (k < EMB) v = (f16)W[k * DM + n];
    Wt[(size_t)n * KPAD + k] = v;                  // scattered 2B writes; 1.3 MB, L2 absorbs
}

__global__ __launch_bounds__(256) void prep_b(const float* __restrict__ b, float* __restrict__ bs) {
    int i = blockIdx.x * 256 + threadIdx.x;
    if (i < DM) bs[i] = b[i] * SCALE;
}

// ---- main GEMM: 128x128 tile, BK=64 x 5 chunks, 4 waves 2x2, 4x4 MFMA 16x16x32 each ----
__global__ __launch_bounds__(256) void embed_gemm(
        const int* __restrict__ x, const float* __restrict__ emb,
        const f16* __restrict__ Wt, const float* __restrict__ bs,
        float* __restrict__ out)
{
    __shared__ __align__(16) f16 As[128 * LDS_STRIDE];
    __shared__ __align__(16) f16 Bs[128 * LDS_STRIDE];
    __shared__ int toks[128];

    const int t = threadIdx.x;
    const int lane = t & 63;
    const int wave = t >> 6;
    const int m0 = blockIdx.y << 7;
    const int n0 = blockIdx.x << 7;
    const int wm = (wave >> 1) << 6;   // wave's 64-row offset in tile
    const int wn = (wave & 1) << 6;    // wave's 64-col offset in tile
    const int quad = lane >> 4;
    const int lr = lane & 15;

    if (t < 128) toks[t] = x[m0 + t];
    __syncthreads();

    f32x4 acc[4][4] = {};

    for (int kc = 0; kc < 5; ++kc) {
        const int k0 = kc << 6;

        // Stage B tile: Bs[n][k] = Wt[n0+n][k0+k]. 2048 4-elem quads, 8 per thread.
        #pragma unroll
        for (int i = 0; i < 8; ++i) {
            int q   = (i << 8) + t;
            int row = q >> 4;          // 16 quads per 64-wide row
            int qc  = q & 15;
            h4 v = *(const h4*)(Wt + (size_t)(n0 + row) * KPAD + k0 + (qc << 2));
            *(h4*)(Bs + row * LDS_STRIDE + (qc << 2)) = v;
        }

        // Stage A tile (gathered emb rows, fp32 -> fp16), zero-fill past K=300.
        #pragma unroll
        for (int i = 0; i < 8; ++i) {
            int q   = (i << 8) + t;
            int row = q >> 4;
            int qc  = q & 15;
            int k   = k0 + (qc << 2);
            h4 hv = {(f16)0.f, (f16)0.f, (f16)0.f, (f16)0.f};
            if (k + 3 < EMB) {   // k is a multiple of 4; 300 % 4 == 0, so no partial quads
                float4 v = *(const float4*)(emb + (size_t)toks[row] * EMB + k);
                hv[0] = (f16)v.x; hv[1] = (f16)v.y; hv[2] = (f16)v.z; hv[3] = (f16)v.w;
            }
            *(h4*)(As + row * LDS_STRIDE + (qc << 2)) = hv;
        }
        __syncthreads();

        #pragma unroll
        for (int kk = 0; kk < 2; ++kk) {   // two K=32 MFMA steps per 64-chunk
            h8 af[4], bfr[4];
            const int c = (kk << 2) + quad;          // 8-element chunk index in [0,8)
            #pragma unroll
            for (int mi = 0; mi < 4; ++mi) {
                int m = wm + (mi << 4) + lr;         // A row this lane needs
                af[mi] = *(const h8*)(As + m * LDS_STRIDE + (c << 3));
            }
            #pragma unroll
            for (int ni = 0; ni < 4; ++ni) {
                int n = wn + (ni << 4) + lr;
                bfr[ni] = *(const h8*)(Bs + n * LDS_STRIDE + (c << 3));
            }
            #pragma unroll
            for (int mi = 0; mi < 4; ++mi)
                #pragma unroll
                for (int ni = 0; ni < 4; ++ni)
                    acc[mi][ni] = __builtin_amdgcn_mfma_f32_16x16x32_f16(
                        af[mi], bfr[ni], acc[mi][ni], 0, 0, 0);
        }
        __syncthreads();
    }

    // epilogue: out = acc*scale + bias(prescaled); C/D layout col=lane&15, row=quad*4+r
    #pragma unroll
    for (int ni = 0; ni < 4; ++ni) {
        int n = n0 + wn + (ni << 4) + lr;
        float bias = bs[n];
        #pragma unroll
        for (int mi = 0; mi < 4; ++mi) {
            int mb = m0 + wm + (mi << 4) + (quad << 2);
            #pragma unroll
            for (int r = 0; r < 4; ++r) {
                out[(size_t)(mb + r) * DM + n] = fmaf(acc[mi][ni][r], SCALE, bias);
            }
        }
    }
}

// ---- correct-but-slow fp32 fallback if ws is too small for Wt ----
__global__ __launch_bounds__(256) void naive_kernel(
        const int* __restrict__ x, const float* __restrict__ emb,
        const float* __restrict__ W, const float* __restrict__ b, float* __restrict__ out)
{
    size_t idx = (size_t)blockIdx.x * 256 + threadIdx.x;
    int n = (int)(idx & (DM - 1));
    size_t m = idx >> 11;
    const float* e = emb + (size_t)x[m] * EMB;
    float a = 0.f;
    for (int k = 0; k < EMB; ++k) a = fmaf(e[k], W[(size_t)k * DM + n], a);
    out[idx] = (a + b[n]) * SCALE;
}

extern "C" void kernel_launch(void* const* d_in, const int* in_sizes, int n_in,
                              void* d_out, int out_size, void* d_ws, size_t ws_size,
                              hipStream_t stream) {
    const int*   x   = (const int*)d_in[0];
    const float* emb = (const float*)d_in[1];
    const float* W   = (const float*)d_in[2];
    const float* b   = (const float*)d_in[3];
    float* out = (float*)d_out;

    const size_t wt_bytes = (size_t)DM * KPAD * sizeof(f16);   // 1,310,720
    const size_t need = wt_bytes + (size_t)DM * sizeof(float); // + 8,192

    if (ws_size >= need) {
        f16* Wt = (f16*)d_ws;
        float* bsp = (float*)((char*)d_ws + wt_bytes);
        prep_w<<<(DM * KPAD) / 256, 256, 0, stream>>>(W, Wt);
        prep_b<<<DM / 256, 256, 0, stream>>>(b, bsp);
        dim3 grid(DM / 128, TOKENS / 128);   // N-tiles fastest -> blocks sharing A rows are adjacent
        embed_gemm<<<grid, 256, 0, stream>>>(x, emb, Wt, bsp, out);
    } else {
        naive_kernel<<<((size_t)TOKENS * DM) / 256, 256, 0, stream>>>(x, emb, W, b, out);
    }
}

// Round 4
// 414.434 us; speedup vs baseline: 1.1241x; 1.1241x over previous
//
#include <hip/hip_runtime.h>
#include <hip/hip_bf16.h>

// out[b,s,:] = (emb[x[b,s],:] @ W + b) * sqrt(2048)
// x:[4,8192] int32, emb:[50000,300] fp32, W:[300,2048] fp32, b:[2048] fp32
// out: [4,8192,2048] fp32.  M=32768 tokens, N=2048, K=300 (padded 320).
// fp16 MFMA (f32_16x16x32_f16), fp32 accumulate + fp32 out.
// LDS: XOR-swizzled, stride 64 halves: chunk c of row r at r*64 + (c^(r&7))*8.
//   - 16B writes: each 8-lane group covers 32 banks once  -> conflict-free
//   - 8B writes: each 16-lane group covers 32 banks once   -> conflict-free
//   - b128 frag reads: 8 distinct 16B addrs/wave, 8-way broadcast -> free
// (Round 3: stride-72 unswizzled cost 5.24M conflict cycles/dispatch = the bottleneck.)

#define TOKENS 32768
#define EMB 300
#define DM 2048
#define KPAD 320
#define SCALE 45.25483399593904f

typedef _Float16 f16;
typedef _Float16 h4 __attribute__((ext_vector_type(4)));
typedef _Float16 h8 __attribute__((ext_vector_type(8)));
typedef float f32x4 __attribute__((ext_vector_type(4)));

// ---- prep: Wt[n][k] = (f16)W[k][n], k zero-padded 300->320; LDS-tiled transpose ----
__global__ __launch_bounds__(256) void prep_w(const float* __restrict__ W, f16* __restrict__ Wt) {
    __shared__ f16 tile[64 * 68];          // [k][n], stride 68 breaks transpose-read conflicts
    const int k0 = blockIdx.x << 6;        // 5 k-tiles
    const int n0 = blockIdx.y << 6;        // 32 n-tiles
    const int t = threadIdx.x;
    #pragma unroll
    for (int i = 0; i < 4; ++i) {
        int idx = (i << 8) + t;            // 64 k-rows x 16 float4
        int kr = idx >> 4;
        int nc = idx & 15;
        h4 hv = {};
        if (k0 + kr < EMB) {
            float4 v = *(const float4*)(W + (size_t)(k0 + kr) * DM + n0 + (nc << 2));
            hv[0]=(f16)v.x; hv[1]=(f16)v.y; hv[2]=(f16)v.z; hv[3]=(f16)v.w;
        }
        *(h4*)(tile + kr * 68 + (nc << 2)) = hv;
    }
    __syncthreads();
    #pragma unroll
    for (int i = 0; i < 4; ++i) {
        int idx = (i << 8) + t;            // 64 n-rows x 16 h4 along k
        int n  = idx >> 4;
        int kc = idx & 15;
        h4 hv;
        hv[0] = tile[(kc * 4 + 0) * 68 + n];
        hv[1] = tile[(kc * 4 + 1) * 68 + n];
        hv[2] = tile[(kc * 4 + 2) * 68 + n];
        hv[3] = tile[(kc * 4 + 3) * 68 + n];
        *(h4*)(Wt + (size_t)(n0 + n) * KPAD + k0 + (kc << 2)) = hv;   // coalesced
    }
}

__global__ __launch_bounds__(256) void prep_b(const float* __restrict__ b, float* __restrict__ bs) {
    int i = blockIdx.x * 256 + threadIdx.x;
    if (i < DM) bs[i] = b[i] * SCALE;
}

// ---- main GEMM: 128x128 tile, BK=64 x 5 chunks, 4 waves 2x2, 4x4 MFMA 16x16x32 ----
__global__ __launch_bounds__(256, 4) void embed_gemm(
        const int* __restrict__ x, const float* __restrict__ emb,
        const f16* __restrict__ Wt, const float* __restrict__ bs,
        float* __restrict__ out)
{
    __shared__ __align__(16) f16 As[128 * 64];
    __shared__ __align__(16) f16 Bs[128 * 64];
    __shared__ int toks[128];

    // XCD-aware remap: all 16 N-tiles of an M-tile run consecutively on one XCD,
    // so the gathered A rows (154 KB) + Wt (1.3 MB) stay in that XCD's 4MB L2.
    const int lin  = blockIdx.x;           // 0..4095
    const int xcd  = lin & 7;
    const int slot = lin >> 3;             // 0..511 within XCD
    const int mtile = (xcd << 5) + (slot >> 4);   // 32 M-tiles per XCD
    const int ntile = slot & 15;
    const int m0 = mtile << 7;
    const int n0 = ntile << 7;

    const int t = threadIdx.x;
    const int lane = t & 63;
    const int wave = t >> 6;
    const int wm = (wave >> 1) << 6;
    const int wn = (wave & 1) << 6;
    const int quad = lane >> 4;
    const int lr = lane & 15;

    if (t < 128) toks[t] = x[m0 + t];
    __syncthreads();

    f32x4 acc[4][4] = {};

    for (int kc = 0; kc < 5; ++kc) {
        const int k0 = kc << 6;

        // Stage B: 128 rows x 8 chunks of h8 (16B), swizzled.
        #pragma unroll
        for (int i = 0; i < 4; ++i) {
            int idx = (i << 8) + t;        // 0..1023
            int row = idx >> 3;
            int c   = idx & 7;
            h8 v = *(const h8*)(Wt + (size_t)(n0 + row) * KPAD + k0 + (c << 3));
            *(h8*)(Bs + (row << 6) + ((c ^ (row & 7)) << 3)) = v;
        }

        // Stage A: gathered emb rows, fp32 float4 -> h4 (8B), swizzled, zero-pad K tail.
        #pragma unroll
        for (int i = 0; i < 8; ++i) {
            int q   = (i << 8) + t;        // 0..2047
            int row = q >> 4;
            int qc  = q & 15;              // 4-half quad within 64-wide row
            int k   = k0 + (qc << 2);
            h4 hv = {};
            if (k + 3 < EMB) {
                float4 v = *(const float4*)(emb + (size_t)toks[row] * EMB + k);
                hv[0]=(f16)v.x; hv[1]=(f16)v.y; hv[2]=(f16)v.z; hv[3]=(f16)v.w;
            }
            int c = qc >> 1, half = qc & 1;
            *(h4*)(As + (row << 6) + (((c ^ (row & 7)) << 3) + (half << 2))) = hv;
        }
        __syncthreads();

        #pragma unroll
        for (int kk = 0; kk < 2; ++kk) {
            h8 af[4], bfr[4];
            const int c = (kk << 2) + quad;
            #pragma unroll
            for (int mi = 0; mi < 4; ++mi) {
                int m = wm + (mi << 4) + lr;
                af[mi] = *(const h8*)(As + (m << 6) + ((c ^ (m & 7)) << 3));
            }
            #pragma unroll
            for (int ni = 0; ni < 4; ++ni) {
                int n = wn + (ni << 4) + lr;
                bfr[ni] = *(const h8*)(Bs + (n << 6) + ((c ^ (n & 7)) << 3));
            }
            #pragma unroll
            for (int mi = 0; mi < 4; ++mi)
                #pragma unroll
                for (int ni = 0; ni < 4; ++ni)
                    acc[mi][ni] = __builtin_amdgcn_mfma_f32_16x16x32_f16(
                        af[mi], bfr[ni], acc[mi][ni], 0, 0, 0);
        }
        __syncthreads();
    }

    // epilogue: C/D layout col=lane&15, row=quad*4+r
    #pragma unroll
    for (int ni = 0; ni < 4; ++ni) {
        int n = n0 + wn + (ni << 4) + lr;
        float bias = bs[n];
        #pragma unroll
        for (int mi = 0; mi < 4; ++mi) {
            int mb = m0 + wm + (mi << 4) + (quad << 2);
            #pragma unroll
            for (int r = 0; r < 4; ++r) {
                out[(size_t)(mb + r) * DM + n] = fmaf(acc[mi][ni][r], SCALE, bias);
            }
        }
    }
}

// ---- correct-but-slow fp32 fallback if ws is too small ----
__global__ __launch_bounds__(256) void naive_kernel(
        const int* __restrict__ x, const float* __restrict__ emb,
        const float* __restrict__ W, const float* __restrict__ b, float* __restrict__ out)
{
    size_t idx = (size_t)blockIdx.x * 256 + threadIdx.x;
    int n = (int)(idx & (DM - 1));
    size_t m = idx >> 11;
    const float* e = emb + (size_t)x[m] * EMB;
    float a = 0.f;
    for (int k = 0; k < EMB; ++k) a = fmaf(e[k], W[(size_t)k * DM + n], a);
    out[idx] = (a + b[n]) * SCALE;
}

extern "C" void kernel_launch(void* const* d_in, const int* in_sizes, int n_in,
                              void* d_out, int out_size, void* d_ws, size_t ws_size,
                              hipStream_t stream) {
    const int*   x   = (const int*)d_in[0];
    const float* emb = (const float*)d_in[1];
    const float* W   = (const float*)d_in[2];
    const float* b   = (const float*)d_in[3];
    float* out = (float*)d_out;

    const size_t wt_bytes = (size_t)DM * KPAD * sizeof(f16);   // 1,310,720
    const size_t need = wt_bytes + (size_t)DM * sizeof(float);

    if (ws_size >= need) {
        f16* Wt = (f16*)d_ws;
        float* bsp = (float*)((char*)d_ws + wt_bytes);
        prep_w<<<dim3(KPAD / 64, DM / 64), 256, 0, stream>>>(W, Wt);
        prep_b<<<DM / 256, 256, 0, stream>>>(b, bsp);
        embed_gemm<<<(TOKENS / 128) * (DM / 128), 256, 0, stream>>>(x, emb, Wt, bsp, out);
    } else {
        naive_kernel<<<((size_t)TOKENS * DM) / 256, 256, 0, stream>>>(x, emb, W, b, out);
    }
}